// Round 9
// baseline (1804.921 us; speedup 1.0000x reference)
//
#include <hip/hip_runtime.h>
#include <hip/hip_bf16.h>

#define N_POL  50000
#define N_TICK 200000
#define N_COMM 5000
#define N_NODES 255000   // N_POL + N_TICK + N_COMM
#define N_EDGES 4000000
#define EMB 32
#define HID 64
#define OUT_D 32

#define NG 1993          // groups of 128 dst rows: ceil(255000/128)
#define NB 250           // buckets of 1024 dst rows: ceil(255000/1024)
#define CHUNK 4096       // edges per passA workgroup
#define NWG_A 977        // ceil(N_EDGES / CHUNK)
#define PARTS 5          // sub-chunks per bucket in passA2

// ---------------------------------------------------------------------------
// K1: fused node embedding + layernorm.  One 32-lane group per node row.
// ---------------------------------------------------------------------------
__global__ __launch_bounds__(256) void k_embed(
    const float* __restrict__ pol_features, const int* __restrict__ state_ids,
    const int* __restrict__ sector_ids, const int* __restrict__ industry_ids,
    const float* __restrict__ comp_extra,
    const float* __restrict__ pol_W, const float* __restrict__ pol_b,
    const float* __restrict__ state_emb, const float* __restrict__ sector_emb,
    const float* __restrict__ industry_emb, const float* __restrict__ comp_W,
    const float* __restrict__ comp_b, const float* __restrict__ comm_emb,
    const float* __restrict__ ln_g, const float* __restrict__ ln_b,
    float* __restrict__ x)
{
    int tid = blockIdx.x * 256 + threadIdx.x;
    int r = tid >> 5;
    int c = tid & 31;
    if (r >= N_NODES) return;

    float acc;
    if (r < N_POL) {
        acc = pol_b[c];
        #pragma unroll
        for (int k = 0; k < 7; ++k)
            acc = fmaf(pol_features[r*7 + k], pol_W[k*EMB + c], acc);
        acc = fmaxf(acc, 0.f);
        acc += state_emb[state_ids[r]*EMB + c];
    } else if (r < N_POL + N_TICK) {
        int i = r - N_POL;
        acc = comp_b[c];
        int sec = sector_ids[i], ind = industry_ids[i];
        #pragma unroll
        for (int k = 0; k < 8; ++k)
            acc = fmaf(sector_emb[sec*8 + k], comp_W[k*EMB + c], acc);
        #pragma unroll
        for (int k = 0; k < 8; ++k)
            acc = fmaf(industry_emb[ind*8 + k], comp_W[(8+k)*EMB + c], acc);
        acc = fmaf(comp_extra[i], comp_W[16*EMB + c], acc);
        acc = fmaxf(acc, 0.f);
    } else {
        acc = comm_emb[(r - N_POL - N_TICK)*EMB + c];
    }

    float s = acc;
    #pragma unroll
    for (int m = 16; m >= 1; m >>= 1) s += __shfl_xor(s, m, 32);
    float mu = s * (1.f/32.f);
    float d  = acc - mu;
    float v  = d * d;
    #pragma unroll
    for (int m = 16; m >= 1; m >>= 1) v += __shfl_xor(v, m, 32);
    v *= (1.f/32.f);
    x[r*EMB + c] = d * rsqrtf(v + 1e-5f) * ln_g[c] + ln_b[c];
}

// ---------------------------------------------------------------------------
// Group histogram: LDS-privatized per WG, then merged to global (curA2 holds
// counts at this stage).
// ---------------------------------------------------------------------------
__global__ __launch_bounds__(256) void k_bhist(const int* __restrict__ ei,
                                               int* __restrict__ gcnt)
{
    __shared__ int h[NG];
    for (int j = threadIdx.x; j < NG; j += 256) h[j] = 0;
    __syncthreads();
    int e0 = blockIdx.x * CHUNK;
    int n  = min(CHUNK, N_EDGES - e0);
    for (int j = threadIdx.x; j < n; j += 256) {
        int d = ei[N_EDGES + e0 + j];
        atomicAdd(&h[d >> 7], 1);
    }
    __syncthreads();
    for (int j = threadIdx.x; j < NG; j += 256)
        if (h[j]) atomicAdd(&gcnt[j], h[j]);
}

// ---------------------------------------------------------------------------
// Scan the NG group counts (single block).  Produces:
//   groupBase[0..NG]  exclusive prefix + sentinel
//   curA2[g] = groupBase[g]   (cursors for passA2 reservations)
//   curA[b]  = groupBase[b*8] (cursors for passA bucket reservations)
// ---------------------------------------------------------------------------
__global__ __launch_bounds__(256) void k_bscan(int* __restrict__ cnt_then_cur,
                                               int* __restrict__ groupBase,
                                               int* __restrict__ curA)
{
    __shared__ int s[256];
    int t = threadIdx.x;
    int v[8];
    int tsum = 0;
    #pragma unroll
    for (int k = 0; k < 8; ++k) {
        int j = t*8 + k;
        v[k] = (j < NG) ? cnt_then_cur[j] : 0;
        tsum += v[k];
    }
    s[t] = tsum;
    __syncthreads();
    for (int off = 1; off < 256; off <<= 1) {
        int u = (t >= off) ? s[t-off] : 0;
        __syncthreads();
        s[t] += u;
        __syncthreads();
    }
    int excl = s[t] - tsum;
    int running = excl;
    #pragma unroll
    for (int k = 0; k < 8; ++k) {
        int j = t*8 + k;
        if (j < NG) {
            groupBase[j] = running;
            cnt_then_cur[j] = running;   // curA2
        }
        running += v[k];
    }
    if (t < NB) curA[t] = excl;          // bucket t base = groupBase[t*8]
    if (t == 250) groupBase[NG] = excl;  // == N_EDGES
}

// ---------------------------------------------------------------------------
// passA: counting-sort edges into NB=250 buckets (dst>>10).  LDS-staged so
// each WG emits ~16-edge grouped runs (full cache lines) instead of 4M
// scattered 8B writes.  Payload packs (dstLocal10 | src18, w).
// ---------------------------------------------------------------------------
__global__ __launch_bounds__(256) void k_passA(const int* __restrict__ ei,
                                               const float* __restrict__ ew,
                                               int* __restrict__ curA,
                                               int2* __restrict__ ce1)
{
    __shared__ int2 stg[CHUNK];
    __shared__ unsigned char aux[CHUNK];
    __shared__ int cnt[256], start[256], mycur[256], goff[256], sc[256];

    int t = threadIdx.x;
    int e0 = blockIdx.x * CHUNK;
    int n  = min(CHUNK, N_EDGES - e0);

    cnt[t] = 0;
    __syncthreads();
    for (int j = t; j < n; j += 256) {
        int d = ei[N_EDGES + e0 + j];
        atomicAdd(&cnt[d >> 10], 1);
    }
    __syncthreads();
    int v = cnt[t];
    sc[t] = v;
    __syncthreads();
    for (int off = 1; off < 256; off <<= 1) {
        int u = (t >= off) ? sc[t-off] : 0;
        __syncthreads();
        sc[t] += u;
        __syncthreads();
    }
    start[t] = sc[t] - v;
    mycur[t] = sc[t] - v;
    if (t < NB && v > 0) goff[t] = atomicAdd(&curA[t], v);
    __syncthreads();

    for (int j = t; j < n; j += 256) {
        int d = ei[N_EDGES + e0 + j];
        int srcv = ei[e0 + j];
        float w = ew[e0 + j];
        int b = d >> 10;
        int slot = atomicAdd(&mycur[b], 1);
        stg[slot] = make_int2(((d & 1023) << 18) | srcv, __float_as_int(w));
        aux[slot] = (unsigned char)b;
    }
    __syncthreads();
    for (int j = t; j < n; j += 256) {
        int b = aux[j];
        ce1[goff[b] + (j - start[b])] = stg[j];
    }
}

// ---------------------------------------------------------------------------
// passA2: within each bucket, partition into its 8 sub-groups (128 rows
// each).  Within-group order arbitrary.  Same LDS-staged grouped-write trick.
// ---------------------------------------------------------------------------
__global__ __launch_bounds__(256) void k_passA2(const int2* __restrict__ ce1,
                                                const int* __restrict__ groupBase,
                                                int* __restrict__ curA2,
                                                int2* __restrict__ ce2)
{
    __shared__ int2 stg[CHUNK];
    __shared__ unsigned char aux[CHUNK];
    __shared__ int cnt[8], start[8], mycur[8], goff[8];

    int t = threadIdx.x;
    int b = blockIdx.x / PARTS;
    int k = blockIdx.x % PARTS;
    int g0 = b * 8;
    int g1 = min(g0 + 8, NG);
    int lo = groupBase[g0];
    int hi = groupBase[g1];
    int len = hi - lo;
    int chunk = (len + PARTS - 1) / PARTS;
    int s0 = lo + k * chunk;
    int s1 = min(s0 + chunk, hi);
    int n = s1 - s0;
    if (n <= 0) return;

    if (t < 8) cnt[t] = 0;
    __syncthreads();
    for (int j = t; j < n; j += 256) {
        int p = ce1[s0 + j].x;
        atomicAdd(&cnt[(p >> 25) & 7], 1);
    }
    __syncthreads();
    if (t == 0) {
        int running = 0;
        #pragma unroll
        for (int s = 0; s < 8; ++s) { start[s] = running; mycur[s] = running; running += cnt[s]; }
    }
    __syncthreads();
    if (t < 8 && cnt[t] > 0) goff[t] = atomicAdd(&curA2[g0 + t], cnt[t]);
    __syncthreads();

    for (int j = t; j < n; j += 256) {
        int2 e = ce1[s0 + j];
        int sub = (e.x >> 25) & 7;
        int slot = atomicAdd(&mycur[sub], 1);
        stg[slot] = e;
        aux[slot] = (unsigned char)sub;
    }
    __syncthreads();
    for (int j = t; j < n; j += 256) {
        int sub = aux[j];
        ce2[goff[sub] + (j - start[sub])] = stg[j];
    }
}

// ---------------------------------------------------------------------------
// bagg: one WG per 128-row group.  LDS f32 accumulate (ds_add_f32,
// bank-conflict-free: lane = column), sequential edge stream, contiguous
// 16 KB output store.  No global atomics, no rowptr.
// ---------------------------------------------------------------------------
__global__ __launch_bounds__(256) void k_bagg(const int* __restrict__ groupBase,
                                              const int2* __restrict__ ce2,
                                              const float* __restrict__ feat,
                                              float* __restrict__ agg)
{
    __shared__ float acc[128 * EMB];   // 16 KB
    int t = threadIdx.x;
    int g = blockIdx.x;

    float4* a4 = (float4*)acc;
    #pragma unroll
    for (int k = 0; k < 4; ++k) a4[t + k*256] = make_float4(0.f, 0.f, 0.f, 0.f);
    __syncthreads();

    int lo = groupBase[g], hi = groupBase[g + 1];
    int grp = t >> 5;
    int c   = t & 31;
    for (int i = lo + grp; i < hi; i += 8) {
        int2 e = ce2[i];
        int row  = (e.x >> 18) & 127;
        int srcv = e.x & 0x3FFFF;
        float w  = __int_as_float(e.y);
        float val = feat[(size_t)srcv * EMB + c] * w;
        __hip_atomic_fetch_add(&acc[row * EMB + c], val,
                               __ATOMIC_RELAXED, __HIP_MEMORY_SCOPE_WORKGROUP);
    }
    __syncthreads();

    int r0 = g * 128;
    int nr = min(128, N_NODES - r0);
    for (int j = t; j < nr * EMB; j += 256)
        agg[(size_t)r0 * EMB + j] = acc[j];
}

// ---------------------------------------------------------------------------
// K3: x1 = relu(agg @ w1_rel + b1 + x @ w1_root)   [N,64]
// One wave per row, lane = output column; weight columns in VGPRs.
// ---------------------------------------------------------------------------
__global__ __launch_bounds__(256) void k_conv1(
    const float* __restrict__ x, const float* __restrict__ agg,
    const float* __restrict__ w1_rel, const float* __restrict__ b1_rel,
    const float* __restrict__ w1_root,
    float* __restrict__ x1)
{
    int lane = threadIdx.x & 63;
    int wid  = threadIdx.x >> 6;

    float wr[32], wt[32];
    #pragma unroll
    for (int k = 0; k < 32; ++k) {
        wr[k] = w1_rel[k*HID + lane];
        wt[k] = w1_root[k*HID + lane];
    }
    float bias = b1_rel[lane];

    int nw = gridDim.x * 4;
    for (int r0 = blockIdx.x*4 + wid; r0 < N_NODES; r0 += nw) {
        int r = __builtin_amdgcn_readfirstlane(r0);
        const float4* xr = (const float4*)(x   + (size_t)r*EMB);
        const float4* ar = (const float4*)(agg + (size_t)r*EMB);
        float a0 = bias, a1 = 0.f, a2 = 0.f, a3 = 0.f;
        #pragma unroll
        for (int i = 0; i < 8; ++i) {
            float4 xv = xr[i];
            float4 av = ar[i];
            a0 = fmaf(xv.x, wt[4*i+0], a0);  a0 = fmaf(av.x, wr[4*i+0], a0);
            a1 = fmaf(xv.y, wt[4*i+1], a1);  a1 = fmaf(av.y, wr[4*i+1], a1);
            a2 = fmaf(xv.z, wt[4*i+2], a2);  a2 = fmaf(av.z, wr[4*i+2], a2);
            a3 = fmaf(xv.w, wt[4*i+3], a3);  a3 = fmaf(av.w, wr[4*i+3], a3);
        }
        x1[(size_t)r*HID + lane] = fmaxf((a0 + a1) + (a2 + a3), 0.f);
    }
}

// ---------------------------------------------------------------------------
// K3b: z = x1 @ w2_rel   [N,32]
// ---------------------------------------------------------------------------
__global__ __launch_bounds__(256) void k_z(
    const float* __restrict__ x1, const float* __restrict__ w2_rel,
    float* __restrict__ z)
{
    int lane = threadIdx.x & 63;
    int wid  = threadIdx.x >> 6;
    int c    = lane & 31;
    int half = lane >> 5;

    float w[32];
    #pragma unroll
    for (int j = 0; j < 32; ++j) w[j] = w2_rel[(half*32 + j)*OUT_D + c];

    int nw = gridDim.x * 4;
    for (int r0 = blockIdx.x*4 + wid; r0 < N_NODES; r0 += nw) {
        int r = __builtin_amdgcn_readfirstlane(r0);
        const float4* xr = (const float4*)(x1 + (size_t)r*HID + half*32);
        float p0 = 0.f, p1 = 0.f, p2 = 0.f, p3 = 0.f;
        #pragma unroll
        for (int i = 0; i < 8; ++i) {
            float4 v = xr[i];
            p0 = fmaf(v.x, w[4*i+0], p0);
            p1 = fmaf(v.y, w[4*i+1], p1);
            p2 = fmaf(v.z, w[4*i+2], p2);
            p3 = fmaf(v.w, w[4*i+3], p3);
        }
        float part = (p0 + p1) + (p2 + p3);
        part += __shfl_xor(part, 32, 64);
        if (lane < 32) z[(size_t)r*EMB + c] = part;
    }
}

// ---------------------------------------------------------------------------
// K5: out = agg2 + b2 + x1 @ w2_root
// ---------------------------------------------------------------------------
__global__ __launch_bounds__(256) void k_out(
    const float* __restrict__ x1, const float* __restrict__ agg,
    const float* __restrict__ w2_root, const float* __restrict__ b2_rel,
    float* __restrict__ out)
{
    int lane = threadIdx.x & 63;
    int wid  = threadIdx.x >> 6;
    int c    = lane & 31;
    int half = lane >> 5;

    float w[32];
    #pragma unroll
    for (int j = 0; j < 32; ++j) w[j] = w2_root[(half*32 + j)*OUT_D + c];
    float bias = b2_rel[c];

    int nw = gridDim.x * 4;
    for (int r0 = blockIdx.x*4 + wid; r0 < N_NODES; r0 += nw) {
        int r = __builtin_amdgcn_readfirstlane(r0);
        const float4* xr = (const float4*)(x1 + (size_t)r*HID + half*32);
        float p0 = 0.f, p1 = 0.f, p2 = 0.f, p3 = 0.f;
        #pragma unroll
        for (int i = 0; i < 8; ++i) {
            float4 v = xr[i];
            p0 = fmaf(v.x, w[4*i+0], p0);
            p1 = fmaf(v.y, w[4*i+1], p1);
            p2 = fmaf(v.z, w[4*i+2], p2);
            p3 = fmaf(v.w, w[4*i+3], p3);
        }
        float part = (p0 + p1) + (p2 + p3);
        part += __shfl_xor(part, 32, 64);
        if (lane < 32)
            out[(size_t)r*OUT_D + c] = part + agg[(size_t)r*EMB + c] + bias;
    }
}

extern "C" void kernel_launch(void* const* d_in, const int* in_sizes, int n_in,
                              void* d_out, int out_size, void* d_ws, size_t ws_size,
                              hipStream_t stream) {
    const float* pol_features = (const float*)d_in[0];
    const int*   state_ids    = (const int*)  d_in[1];
    const int*   sector_ids   = (const int*)  d_in[2];
    const int*   industry_ids = (const int*)  d_in[3];
    const float* comp_extra   = (const float*)d_in[4];
    const int*   edge_index   = (const int*)  d_in[5];
    const float* edge_weight  = (const float*)d_in[6];
    const float* pol_W        = (const float*)d_in[7];
    const float* pol_b        = (const float*)d_in[8];
    const float* state_emb    = (const float*)d_in[9];
    const float* sector_emb   = (const float*)d_in[10];
    const float* industry_emb = (const float*)d_in[11];
    const float* comp_W       = (const float*)d_in[12];
    const float* comp_b       = (const float*)d_in[13];
    const float* comm_emb     = (const float*)d_in[14];
    const float* ln_g         = (const float*)d_in[15];
    const float* ln_b         = (const float*)d_in[16];
    const float* w1_rel       = (const float*)d_in[17];
    const float* b1_rel       = (const float*)d_in[18];
    const float* w1_root      = (const float*)d_in[19];
    const float* w2_rel       = (const float*)d_in[20];
    const float* b2_rel       = (const float*)d_in[21];
    const float* w2_root      = (const float*)d_in[22];

    // workspace layout (f32 units unless noted):
    //   x/z [N*32] | x1 [N*64] (ce1 int2[E]=32MB aliases its head; x1 written
    //   only after passA2 consumes ce1) | agg [N*32] | ce2 int2[E] |
    //   groupBase[NG+1] | curA2[NG] | curA[NB]
    float* x   = (float*)d_ws;
    float* x1  = x  + (size_t)N_NODES * EMB;
    float* agg = x1 + (size_t)N_NODES * HID;
    int2*  ce2 = (int2*)(agg + (size_t)N_NODES * EMB);
    int*   groupBase = (int*)(ce2 + N_EDGES);
    int*   curA2     = groupBase + NG + 8;
    int*   curA      = curA2 + NG + 8;
    int2*  ce1 = (int2*)x1;
    float* out = (float*)d_out;

    // counts accumulate in curA2 (bscan converts to bases in-place)
    hipMemsetAsync(curA2, 0, NG * sizeof(int), stream);

    k_embed<<<(N_NODES*32 + 255)/256, 256, 0, stream>>>(
        pol_features, state_ids, sector_ids, industry_ids, comp_extra,
        pol_W, pol_b, state_emb, sector_emb, industry_emb, comp_W, comp_b,
        comm_emb, ln_g, ln_b, x);

    k_bhist<<<NWG_A, 256, 0, stream>>>(edge_index, curA2);
    k_bscan<<<1, 256, 0, stream>>>(curA2, groupBase, curA);
    k_passA<<<NWG_A, 256, 0, stream>>>(edge_index, edge_weight, curA, ce1);
    k_passA2<<<NB*PARTS, 256, 0, stream>>>(ce1, groupBase, curA2, ce2);

    // conv1
    k_bagg<<<NG, 256, 0, stream>>>(groupBase, ce2, x, agg);
    k_conv1<<<4096, 256, 0, stream>>>(x, agg, w1_rel, b1_rel, w1_root, x1);
    k_z<<<4096, 256, 0, stream>>>(x1, w2_rel, /*z aliases x*/ x);

    // conv2
    k_bagg<<<NG, 256, 0, stream>>>(groupBase, ce2, /*z*/ x, agg);
    k_out<<<4096, 256, 0, stream>>>(x1, agg, w2_root, b2_rel, out);
}